// Round 2
// baseline (1883.815 us; speedup 1.0000x reference)
//
#include <hip/hip_runtime.h>
#include <hip/hip_bf16.h>

typedef __bf16 bf16;
typedef bf16 bf16x8 __attribute__((ext_vector_type(8)));
typedef float f32x4 __attribute__((ext_vector_type(4)));

#define B_N 8192
#define DE_N 256
#define DA_N 32
#define F_N 2048
#define H_N 2048

typedef __attribute__((address_space(1))) void as1_void;
typedef __attribute__((address_space(3))) void as3_void;

static __device__ __forceinline__ void gload16(const void* g, void* l) {
    __builtin_amdgcn_global_load_lds((as1_void*)g, (as3_void*)l, 16, 0, 0);
}

// ---------------- fp32 -> bf16 convert (8 elems / thread) ----------------
__global__ __launch_bounds__(256) void k_convert(const float* __restrict__ src,
                                                 bf16* __restrict__ dst, int n8) {
    int t = blockIdx.x * 256 + threadIdx.x;
    if (t >= n8) return;
    size_t e = (size_t)t * 8;
    f32x4 a = *(const f32x4*)(src + e);
    f32x4 b = *(const f32x4*)(src + e + 4);
    bf16x8 o;
    o[0] = (bf16)a[0]; o[1] = (bf16)a[1]; o[2] = (bf16)a[2]; o[3] = (bf16)a[3];
    o[4] = (bf16)b[0]; o[5] = (bf16)b[1]; o[6] = (bf16)b[2]; o[7] = (bf16)b[3];
    *(bf16x8*)(dst + e) = o;
}

// ---------------- split state -> env_bf16, h0_bf16 ----------------
__global__ __launch_bounds__(256) void k_split_state(const float* __restrict__ state,
                                                     bf16* __restrict__ env,
                                                     bf16* __restrict__ h0, int n8) {
    int t = blockIdx.x * 256 + threadIdx.x;
    if (t >= n8) return;
    unsigned e = (unsigned)t * 8u;
    unsigned row = e / 2304u;
    unsigned col = e - row * 2304u;
    const float* s = state + (size_t)row * 2304 + col;
    f32x4 a = *(const f32x4*)s;
    f32x4 b = *(const f32x4*)(s + 4);
    bf16x8 o;
    o[0] = (bf16)a[0]; o[1] = (bf16)a[1]; o[2] = (bf16)a[2]; o[3] = (bf16)a[3];
    o[4] = (bf16)b[0]; o[5] = (bf16)b[1]; o[6] = (bf16)b[2]; o[7] = (bf16)b[3];
    if (col < 256u) {
        *(bf16x8*)(env + (size_t)row * 256 + col) = o;
    } else {
        *(bf16x8*)(h0 + (size_t)row * 2048 + (col - 256u)) = o;
    }
}

// ---------------- GEMM: C = act(A @ Bw^T + bias) ----------------
// A: M x K bf16 (lda), Bw: N x K bf16 (ldb). 128x128 tile, BK=32, 4 waves.
template<int ACT>
__global__ __launch_bounds__(256)
void k_gemm(const bf16* __restrict__ A, int lda,
            const bf16* __restrict__ Bw, int ldb,
            const float* __restrict__ bias,
            bf16* __restrict__ Cp, int ldc, int K)
{
    __shared__ __align__(16) bf16 As[128 * 32];
    __shared__ __align__(16) bf16 Bs[128 * 32];
    const int t = threadIdx.x;
    const int l = t & 63;
    const int w = t >> 6;
    const int brow = blockIdx.x * 128;
    const int bcol = blockIdx.y * 128;
    const int wr = (w >> 1) * 64;
    const int wc = (w & 1) * 64;

    const int e1 = t * 8;          // staging element offset (8 bf16 = 16 B)
    const int r1 = e1 >> 5;
    const int c1 = e1 & 31;

    f32x4 zero = {0.f, 0.f, 0.f, 0.f};
    f32x4 acc[4][4];
#pragma unroll
    for (int i = 0; i < 4; ++i)
#pragma unroll
        for (int j = 0; j < 4; ++j) acc[i][j] = zero;

    const bf16* ga1 = A + (size_t)(brow + r1) * lda + c1;
    const bf16* ga2 = A + (size_t)(brow + r1 + 64) * lda + c1;
    const bf16* gb1 = Bw + (size_t)(bcol + r1) * ldb + c1;
    const bf16* gb2 = Bw + (size_t)(bcol + r1 + 64) * ldb + c1;

    const int koff = (l >> 4) * 8;
    const int rofs = (l & 15) * 32 + koff;   // within-tile frag base (elements)

    for (int k0 = 0; k0 < K; k0 += 32) {
        gload16(ga1 + k0, &As[e1]);
        gload16(ga2 + k0, &As[e1 + 2048]);
        gload16(gb1 + k0, &Bs[e1]);
        gload16(gb2 + k0, &Bs[e1 + 2048]);
        __syncthreads();
        bf16x8 af[4], bfr[4];
#pragma unroll
        for (int i = 0; i < 4; ++i) af[i] = *(const bf16x8*)&As[(wr + i * 16) * 32 + rofs];
#pragma unroll
        for (int j = 0; j < 4; ++j) bfr[j] = *(const bf16x8*)&Bs[(wc + j * 16) * 32 + rofs];
#pragma unroll
        for (int i = 0; i < 4; ++i)
#pragma unroll
            for (int j = 0; j < 4; ++j)
                acc[i][j] = __builtin_amdgcn_mfma_f32_16x16x32_bf16(af[i], bfr[j], acc[i][j], 0, 0, 0);
        __syncthreads();
    }

    const int crow = brow + wr + (l >> 4) * 4;
    const int ccol = bcol + wc + (l & 15);
#pragma unroll
    for (int j = 0; j < 4; ++j) {
        const int col = ccol + j * 16;
        const float bv = bias[col];
#pragma unroll
        for (int i = 0; i < 4; ++i) {
#pragma unroll
            for (int q = 0; q < 4; ++q) {
                float v = acc[i][j][q] + bv;
                if (ACT) v = fmaxf(v, 0.f);
                Cp[(size_t)(crow + i * 16 + q) * ldc + col] = (bf16)v;
            }
        }
    }
}

// ---------------- GRU gate fusion (per chunk) ----------------
__global__ __launch_bounds__(256) void k_gate(const bf16* __restrict__ gi,
                                              const bf16* __restrict__ gh,
                                              const float* __restrict__ state,
                                              float* __restrict__ nh_out,
                                              bf16* __restrict__ h1_out, int n8) {
    int t = blockIdx.x * 256 + threadIdx.x;
    if (t >= n8) return;
    unsigned e = (unsigned)t * 8u;
    unsigned m = e >> 11;
    unsigned j = e & 2047u;
    const bf16* pgi = gi + (size_t)m * 6144 + j;
    const bf16* pgh = gh + (size_t)m * 6144 + j;
    bf16x8 ir8 = *(const bf16x8*)(pgi);
    bf16x8 iz8 = *(const bf16x8*)(pgi + 2048);
    bf16x8 in8 = *(const bf16x8*)(pgi + 4096);
    bf16x8 hr8 = *(const bf16x8*)(pgh);
    bf16x8 hz8 = *(const bf16x8*)(pgh + 2048);
    bf16x8 hn8 = *(const bf16x8*)(pgh + 4096);
    const float* ph0 = state + (size_t)m * 2304 + 256 + j;
    f32x4 h0a = *(const f32x4*)ph0;
    f32x4 h0b = *(const f32x4*)(ph0 + 4);
    f32x4 nha, nhb;
    bf16x8 h1o;
#pragma unroll
    for (int q = 0; q < 8; ++q) {
        float h0 = (q < 4) ? h0a[q] : h0b[q - 4];
        float r = 1.f / (1.f + __expf(-((float)ir8[q] + (float)hr8[q])));
        float z = 1.f / (1.f + __expf(-((float)iz8[q] + (float)hz8[q])));
        float n = tanhf((float)in8[q] + r * (float)hn8[q]);
        float h1 = (1.f - z) * n + z * h0;
        float nh = 0.5f * (h0 + h1);
        if (q < 4) nha[q] = nh; else nhb[q - 4] = nh;
        h1o[q] = (bf16)h1;
    }
    float* pnh = nh_out + (size_t)m * 2048 + j;
    *(f32x4*)pnh = nha;
    *(f32x4*)(pnh + 4) = nhb;
    *(bf16x8*)(h1_out + (size_t)m * 2048 + j) = h1o;
}

// ---------------- last layer: action = tanh([feat_post, h1] @ W3^T + b3) ----------------
__global__ __launch_bounds__(256) void k_last(const bf16* __restrict__ fpost,
                                              const bf16* __restrict__ h1,
                                              const float* __restrict__ W3,
                                              const float* __restrict__ b3,
                                              float* __restrict__ out) {
    const int m = blockIdx.x * 8 + (threadIdx.x >> 5);
    const int n = threadIdx.x & 31;
    const bf16* pf = fpost + (size_t)m * 2048;
    const bf16* ph = h1 + (size_t)m * 2048;
    const float* w0 = W3 + (size_t)n * 4096;
    const float* w1 = w0 + 2048;
    float acc = 0.f;
    for (int k = 0; k < 2048; k += 8) {
        bf16x8 a = *(const bf16x8*)(pf + k);
        f32x4 wa = *(const f32x4*)(w0 + k);
        f32x4 wb = *(const f32x4*)(w0 + k + 4);
        acc += (float)a[0] * wa[0] + (float)a[1] * wa[1] + (float)a[2] * wa[2] + (float)a[3] * wa[3];
        acc += (float)a[4] * wb[0] + (float)a[5] * wb[1] + (float)a[6] * wb[2] + (float)a[7] * wb[3];
        bf16x8 b = *(const bf16x8*)(ph + k);
        f32x4 wc = *(const f32x4*)(w1 + k);
        f32x4 wd = *(const f32x4*)(w1 + k + 4);
        acc += (float)b[0] * wc[0] + (float)b[1] * wc[1] + (float)b[2] * wc[2] + (float)b[3] * wc[3];
        acc += (float)b[4] * wd[0] + (float)b[5] * wd[1] + (float)b[6] * wd[2] + (float)b[7] * wd[3];
    }
    acc += b3[n];
    out[(size_t)m * 32 + n] = tanhf(acc);
}

// ---------------- launch ----------------
extern "C" void kernel_launch(void* const* d_in, const int* in_sizes, int n_in,
                              void* d_out, int out_size, void* d_ws, size_t ws_size,
                              hipStream_t stream) {
    const float* state = (const float*)d_in[0];
    const float* prev_action = (const float*)d_in[1];
    const float* W_o = (const float*)d_in[2];
    const float* b_o = (const float*)d_in[3];
    const float* W_a = (const float*)d_in[4];
    const float* b_a = (const float*)d_in[5];
    const float* W_post = (const float*)d_in[6];
    const float* b_post = (const float*)d_in[7];
    const float* W_ih = (const float*)d_in[8];
    const float* W_hh = (const float*)d_in[9];
    const float* b_ih = (const float*)d_in[10];
    const float* b_hh = (const float*)d_in[11];
    const float* W3 = (const float*)d_in[12];
    const float* b3 = (const float*)d_in[13];

    float* out_action = (float*)d_out;                    // 8192 x 32
    float* out_nh = (float*)d_out + (size_t)B_N * DA_N;   // 8192 x 2048

    // ---- workspace carve (fixed part ~110.6 MB) ----
    char* p = (char*)d_ws;
    auto carve = [&](size_t bytes) { char* r = p; p += (bytes + 255) & ~(size_t)255; return r; };
    bf16* W_ih_b = (bf16*)carve((size_t)6144 * 4096 * 2);   // 48 MB
    bf16* W_hh_b = (bf16*)carve((size_t)6144 * 2048 * 2);   // 24 MB
    bf16* W_o_b  = (bf16*)carve((size_t)2048 * 256 * 2);
    bf16* W_a_b  = (bf16*)carve((size_t)2048 * 32 * 2);
    bf16* W_p_b  = (bf16*)carve((size_t)2048 * 256 * 2);
    bf16* env_b  = (bf16*)carve((size_t)B_N * 256 * 2);     // 4 MB
    bf16* pa_b   = (bf16*)carve((size_t)B_N * 32 * 2);
    bf16* h0_b   = (bf16*)carve((size_t)B_N * 2048 * 2);    // 32 MB
    size_t fixed = (size_t)(p - (char*)d_ws);

    // ---- chunk size: per-chunk buffers cost C*20480*2 bytes ----
    int C = 2048;
    while (C > 256 && fixed + (size_t)C * 20480 * 2 + 4096 > ws_size) C >>= 1;
    bf16* x_c  = (bf16*)carve((size_t)C * 4096 * 2);
    bf16* fp_c = (bf16*)carve((size_t)C * 2048 * 2);
    bf16* gi_c = (bf16*)carve((size_t)C * 6144 * 2);
    bf16* gh_c = (bf16*)carve((size_t)C * 6144 * 2);
    bf16* h1_c = (bf16*)carve((size_t)C * 2048 * 2);

    // ---- converts ----
    {
        int n8 = 6144 * 4096 / 8;
        k_convert<<<n8 / 256, 256, 0, stream>>>(W_ih, W_ih_b, n8);
    }
    {
        int n8 = 6144 * 2048 / 8;
        k_convert<<<n8 / 256, 256, 0, stream>>>(W_hh, W_hh_b, n8);
    }
    {
        int n8 = 2048 * 256 / 8;
        k_convert<<<n8 / 256, 256, 0, stream>>>(W_o, W_o_b, n8);
        k_convert<<<n8 / 256, 256, 0, stream>>>(W_post, W_p_b, n8);
    }
    {
        int n8 = 2048 * 32 / 8;
        k_convert<<<n8 / 256, 256, 0, stream>>>(W_a, W_a_b, n8);
    }
    {
        int n8 = B_N * 2304 / 8;
        k_split_state<<<n8 / 256, 256, 0, stream>>>(state, env_b, h0_b, n8);
    }
    {
        int n8 = B_N * 32 / 8;
        k_convert<<<n8 / 256, 256, 0, stream>>>(prev_action, pa_b, n8);
    }

    // ---- chunked middle section ----
    const int nch = B_N / C;
    for (int c = 0; c < nch; ++c) {
        const bf16* envc = env_b + (size_t)c * C * 256;
        const bf16* pac  = pa_b + (size_t)c * C * 32;
        const bf16* h0c  = h0_b + (size_t)c * C * 2048;
        const float* stc = state + (size_t)c * C * 2304;
        float* nhc = out_nh + (size_t)c * C * 2048;
        float* acc = out_action + (size_t)c * C * 32;

        dim3 gf(C / 128, F_N / 128);
        // feat_o -> x[:, 0:2048]
        k_gemm<1><<<gf, 256, 0, stream>>>(envc, 256, W_o_b, 256, b_o, x_c, 4096, 256);
        // feat_a -> x[:, 2048:4096]
        k_gemm<1><<<gf, 256, 0, stream>>>(pac, 32, W_a_b, 32, b_a, x_c + 2048, 4096, 32);
        // feat_post
        k_gemm<1><<<gf, 256, 0, stream>>>(envc, 256, W_p_b, 256, b_post, fp_c, 2048, 256);

        dim3 gg(C / 128, 6144 / 128);
        k_gemm<0><<<gg, 256, 0, stream>>>(x_c, 4096, W_ih_b, 4096, b_ih, gi_c, 6144, 4096);
        k_gemm<0><<<gg, 256, 0, stream>>>(h0c, 2048, W_hh_b, 2048, b_hh, gh_c, 6144, 2048);

        int n8 = C * H_N / 8;
        k_gate<<<n8 / 256, 256, 0, stream>>>(gi_c, gh_c, stc, nhc, h1_c, n8);

        k_last<<<C / 8, 256, 0, stream>>>(fp_c, h1_c, W3, b3, acc);
    }
}

// Round 3
// 1264.278 us; speedup vs baseline: 1.4900x; 1.4900x over previous
//
#include <hip/hip_runtime.h>
#include <hip/hip_bf16.h>

typedef __bf16 bf16;
typedef bf16 bf16x8 __attribute__((ext_vector_type(8)));
typedef float f32x4 __attribute__((ext_vector_type(4)));

#define B_N 8192
#define DE_N 256
#define DA_N 32
#define F_N 2048
#define H_N 2048

typedef __attribute__((address_space(1))) void as1_void;
typedef __attribute__((address_space(3))) void as3_void;

static __device__ __forceinline__ void gload16(const void* g, void* l) {
    __builtin_amdgcn_global_load_lds((as1_void*)g, (as3_void*)l, 16, 0, 0);
}

// ---------------- fp32 -> bf16 convert (8 elems / thread) ----------------
__global__ __launch_bounds__(256) void k_convert(const float* __restrict__ src,
                                                 bf16* __restrict__ dst, int n8) {
    int t = blockIdx.x * 256 + threadIdx.x;
    if (t >= n8) return;
    size_t e = (size_t)t * 8;
    f32x4 a = *(const f32x4*)(src + e);
    f32x4 b = *(const f32x4*)(src + e + 4);
    bf16x8 o;
    o[0] = (bf16)a[0]; o[1] = (bf16)a[1]; o[2] = (bf16)a[2]; o[3] = (bf16)a[3];
    o[4] = (bf16)b[0]; o[5] = (bf16)b[1]; o[6] = (bf16)b[2]; o[7] = (bf16)b[3];
    *(bf16x8*)(dst + e) = o;
}

// ---------------- split state -> env_bf16, h0_bf16 ----------------
__global__ __launch_bounds__(256) void k_split_state(const float* __restrict__ state,
                                                     bf16* __restrict__ env,
                                                     bf16* __restrict__ h0, int n8) {
    int t = blockIdx.x * 256 + threadIdx.x;
    if (t >= n8) return;
    unsigned e = (unsigned)t * 8u;
    unsigned row = e / 2304u;
    unsigned col = e - row * 2304u;
    const float* s = state + (size_t)row * 2304 + col;
    f32x4 a = *(const f32x4*)s;
    f32x4 b = *(const f32x4*)(s + 4);
    bf16x8 o;
    o[0] = (bf16)a[0]; o[1] = (bf16)a[1]; o[2] = (bf16)a[2]; o[3] = (bf16)a[3];
    o[4] = (bf16)b[0]; o[5] = (bf16)b[1]; o[6] = (bf16)b[2]; o[7] = (bf16)b[3];
    if (col < 256u) {
        *(bf16x8*)(env + (size_t)row * 256 + col) = o;
    } else {
        *(bf16x8*)(h0 + (size_t)row * 2048 + (col - 256u)) = o;
    }
}

// ---------------- GEMM: C = act(A @ Bw^T + bias) ----------------
// A: M x K bf16 (lda), Bw: N x K bf16 (ldb). 128x128 tile, BK=32, 4 waves.
template<int ACT>
__global__ __launch_bounds__(256)
void k_gemm(const bf16* __restrict__ A, int lda,
            const bf16* __restrict__ Bw, int ldb,
            const float* __restrict__ bias,
            bf16* __restrict__ Cp, int ldc, int K)
{
    __shared__ __align__(16) bf16 As[128 * 32];
    __shared__ __align__(16) bf16 Bs[128 * 32];
    const int t = threadIdx.x;
    const int l = t & 63;
    const int w = t >> 6;
    const int brow = blockIdx.x * 128;
    const int bcol = blockIdx.y * 128;
    const int wr = (w >> 1) * 64;
    const int wc = (w & 1) * 64;

    const int e1 = t * 8;          // staging element offset (8 bf16 = 16 B)
    const int r1 = e1 >> 5;
    const int c1 = e1 & 31;

    f32x4 zero = {0.f, 0.f, 0.f, 0.f};
    f32x4 acc[4][4];
#pragma unroll
    for (int i = 0; i < 4; ++i)
#pragma unroll
        for (int j = 0; j < 4; ++j) acc[i][j] = zero;

    const bf16* ga1 = A + (size_t)(brow + r1) * lda + c1;
    const bf16* ga2 = A + (size_t)(brow + r1 + 64) * lda + c1;
    const bf16* gb1 = Bw + (size_t)(bcol + r1) * ldb + c1;
    const bf16* gb2 = Bw + (size_t)(bcol + r1 + 64) * ldb + c1;

    const int koff = (l >> 4) * 8;
    const int rofs = (l & 15) * 32 + koff;   // within-tile frag base (elements)

    for (int k0 = 0; k0 < K; k0 += 32) {
        gload16(ga1 + k0, &As[e1]);
        gload16(ga2 + k0, &As[e1 + 2048]);
        gload16(gb1 + k0, &Bs[e1]);
        gload16(gb2 + k0, &Bs[e1 + 2048]);
        __syncthreads();
        bf16x8 af[4], bfr[4];
#pragma unroll
        for (int i = 0; i < 4; ++i) af[i] = *(const bf16x8*)&As[(wr + i * 16) * 32 + rofs];
#pragma unroll
        for (int j = 0; j < 4; ++j) bfr[j] = *(const bf16x8*)&Bs[(wc + j * 16) * 32 + rofs];
#pragma unroll
        for (int i = 0; i < 4; ++i)
#pragma unroll
            for (int j = 0; j < 4; ++j)
                acc[i][j] = __builtin_amdgcn_mfma_f32_16x16x32_bf16(af[i], bfr[j], acc[i][j], 0, 0, 0);
        __syncthreads();
    }

    const int crow = brow + wr + (l >> 4) * 4;
    const int ccol = bcol + wc + (l & 15);
#pragma unroll
    for (int j = 0; j < 4; ++j) {
        const int col = ccol + j * 16;
        const float bv = bias[col];
#pragma unroll
        for (int i = 0; i < 4; ++i) {
#pragma unroll
            for (int q = 0; q < 4; ++q) {
                float v = acc[i][j][q] + bv;
                if (ACT) v = fmaxf(v, 0.f);
                Cp[(size_t)(crow + i * 16 + q) * ldc + col] = (bf16)v;
            }
        }
    }
}

// ---------------- GRU gate fusion (per chunk) ----------------
// Writes next_hidden (fp32) to d_out and h1 (bf16) — h1 is written OVER the
// h0_b chunk slice (dead after the gh GEMM of this chunk).
__global__ __launch_bounds__(256) void k_gate(const bf16* __restrict__ gi,
                                              const bf16* __restrict__ gh,
                                              const float* __restrict__ state,
                                              float* __restrict__ nh_out,
                                              bf16* __restrict__ h1_out, int n8) {
    int t = blockIdx.x * 256 + threadIdx.x;
    if (t >= n8) return;
    unsigned e = (unsigned)t * 8u;
    unsigned m = e >> 11;
    unsigned j = e & 2047u;
    const bf16* pgi = gi + (size_t)m * 6144 + j;
    const bf16* pgh = gh + (size_t)m * 6144 + j;
    bf16x8 ir8 = *(const bf16x8*)(pgi);
    bf16x8 iz8 = *(const bf16x8*)(pgi + 2048);
    bf16x8 in8 = *(const bf16x8*)(pgi + 4096);
    bf16x8 hr8 = *(const bf16x8*)(pgh);
    bf16x8 hz8 = *(const bf16x8*)(pgh + 2048);
    bf16x8 hn8 = *(const bf16x8*)(pgh + 4096);
    const float* ph0 = state + (size_t)m * 2304 + 256 + j;
    f32x4 h0a = *(const f32x4*)ph0;
    f32x4 h0b = *(const f32x4*)(ph0 + 4);
    f32x4 nha, nhb;
    bf16x8 h1o;
#pragma unroll
    for (int q = 0; q < 8; ++q) {
        float h0 = (q < 4) ? h0a[q] : h0b[q - 4];
        float r = 1.f / (1.f + __expf(-((float)ir8[q] + (float)hr8[q])));
        float z = 1.f / (1.f + __expf(-((float)iz8[q] + (float)hz8[q])));
        float n = tanhf((float)in8[q] + r * (float)hn8[q]);
        float h1 = (1.f - z) * n + z * h0;
        float nh = 0.5f * (h0 + h1);
        if (q < 4) nha[q] = nh; else nhb[q - 4] = nh;
        h1o[q] = (bf16)h1;
    }
    float* pnh = nh_out + (size_t)m * 2048 + j;
    *(f32x4*)pnh = nha;
    *(f32x4*)(pnh + 4) = nhb;
    *(bf16x8*)(h1_out + (size_t)m * 2048 + j) = h1o;
}

// ---------------- last layer (full batch, MFMA, split-K over waves) ----------------
// action = tanh([fpost, h1] @ W3b^T + b3).  M=8192, N=32, K=4096.
// Block: 256 threads = 4 waves; 64 rows x 32 cols per block.
// Wave w covers K-range [w*1024, (w+1)*1024): w=0,1 -> fpost, w=2,3 -> h1.
__global__ __launch_bounds__(256) void k_last(const bf16* __restrict__ fpost,
                                              const bf16* __restrict__ h1,
                                              const bf16* __restrict__ W3b,
                                              const float* __restrict__ b3,
                                              float* __restrict__ out) {
    __shared__ float red[4][64][32];   // 32 KB
    const int t = threadIdx.x;
    const int l = t & 63;
    const int w = t >> 6;
    const int r0 = blockIdx.x * 64;

    const bf16* src = (w < 2) ? fpost : h1;
    const int kbase = (w & 1) * 1024 + (l >> 4) * 8;   // local K offset within src
    const int kw3 = w * 1024 + (l >> 4) * 8;           // K offset within W3 row
    const int ar = l & 15;

    f32x4 zero = {0.f, 0.f, 0.f, 0.f};
    f32x4 acc[4][2];
#pragma unroll
    for (int i = 0; i < 4; ++i) { acc[i][0] = zero; acc[i][1] = zero; }

    const bf16* pa = src + (size_t)(r0 + ar) * 2048 + kbase;
    const bf16* pb0 = W3b + (size_t)ar * 4096 + kw3;
    const bf16* pb1 = W3b + (size_t)(16 + ar) * 4096 + kw3;

    for (int it = 0; it < 32; ++it) {
        const int ko = it * 32;
        bf16x8 bf0 = *(const bf16x8*)(pb0 + ko);
        bf16x8 bf1 = *(const bf16x8*)(pb1 + ko);
        bf16x8 af[4];
#pragma unroll
        for (int i = 0; i < 4; ++i)
            af[i] = *(const bf16x8*)(pa + (size_t)i * 16 * 2048 + ko);
#pragma unroll
        for (int i = 0; i < 4; ++i) {
            acc[i][0] = __builtin_amdgcn_mfma_f32_16x16x32_bf16(af[i], bf0, acc[i][0], 0, 0, 0);
            acc[i][1] = __builtin_amdgcn_mfma_f32_16x16x32_bf16(af[i], bf1, acc[i][1], 0, 0, 0);
        }
    }

    // write partials to LDS
#pragma unroll
    for (int i = 0; i < 4; ++i)
#pragma unroll
        for (int j = 0; j < 2; ++j)
#pragma unroll
            for (int q = 0; q < 4; ++q)
                red[w][i * 16 + (l >> 4) * 4 + q][j * 16 + (l & 15)] = acc[i][j][q];
    __syncthreads();

    // reduce: thread t -> row = t>>2, cols (t&3)*8 .. +7
    const int m = t >> 2;
    const int nb = (t & 3) * 8;
    f32x4 s0 = zero, s1 = zero;
#pragma unroll
    for (int ww = 0; ww < 4; ++ww) {
        s0 += *(const f32x4*)&red[ww][m][nb];
        s1 += *(const f32x4*)&red[ww][m][nb + 4];
    }
    f32x4 bb0 = *(const f32x4*)(b3 + nb);
    f32x4 bb1 = *(const f32x4*)(b3 + nb + 4);
    float* po = out + (size_t)(r0 + m) * 32 + nb;
#pragma unroll
    for (int q = 0; q < 4; ++q) {
        po[q] = tanhf(s0[q] + bb0[q]);
        po[q + 4] = tanhf(s1[q] + bb1[q]);
    }
}

// ---------------- launch ----------------
extern "C" void kernel_launch(void* const* d_in, const int* in_sizes, int n_in,
                              void* d_out, int out_size, void* d_ws, size_t ws_size,
                              hipStream_t stream) {
    const float* state = (const float*)d_in[0];
    const float* prev_action = (const float*)d_in[1];
    const float* W_o = (const float*)d_in[2];
    const float* b_o = (const float*)d_in[3];
    const float* W_a = (const float*)d_in[4];
    const float* b_a = (const float*)d_in[5];
    const float* W_post = (const float*)d_in[6];
    const float* b_post = (const float*)d_in[7];
    const float* W_ih = (const float*)d_in[8];
    const float* W_hh = (const float*)d_in[9];
    const float* b_ih = (const float*)d_in[10];
    const float* b_hh = (const float*)d_in[11];
    const float* W3 = (const float*)d_in[12];
    const float* b3 = (const float*)d_in[13];

    float* out_action = (float*)d_out;                    // 8192 x 32
    float* out_nh = (float*)d_out + (size_t)B_N * DA_N;   // 8192 x 2048

    // ---- workspace carve: fixed part ----
    char* p = (char*)d_ws;
    auto carve = [&](size_t bytes) { char* r = p; p += (bytes + 255) & ~(size_t)255; return r; };
    bf16* W_ih_b = (bf16*)carve((size_t)6144 * 4096 * 2);   // 48 MB
    bf16* W_hh_b = (bf16*)carve((size_t)6144 * 2048 * 2);   // 24 MB
    bf16* W_o_b  = (bf16*)carve((size_t)2048 * 256 * 2);
    bf16* W_a_b  = (bf16*)carve((size_t)2048 * 32 * 2);
    bf16* W_p_b  = (bf16*)carve((size_t)2048 * 256 * 2);
    bf16* W3_b   = (bf16*)carve((size_t)32 * 4096 * 2);
    bf16* env_b  = (bf16*)carve((size_t)B_N * 256 * 2);     // 4 MB
    bf16* pa_b   = (bf16*)carve((size_t)B_N * 32 * 2);
    bf16* h0_b   = (bf16*)carve((size_t)B_N * 2048 * 2);    // 32 MB (becomes h1)
    bf16* fp_b   = (bf16*)carve((size_t)B_N * 2048 * 2);    // 32 MB (full feat_post)
    size_t fixed = (size_t)(p - (char*)d_ws);

    // ---- chunk size: per-chunk buffers (x, gi, gh) cost C*16384*2 bytes ----
    int C = 4096;
    while (C > 256 && fixed + (size_t)C * 16384 * 2 + 4096 > ws_size) C >>= 1;
    bf16* x_c  = (bf16*)carve((size_t)C * 4096 * 2);
    bf16* gi_c = (bf16*)carve((size_t)C * 6144 * 2);
    bf16* gh_c = (bf16*)carve((size_t)C * 6144 * 2);

    // ---- converts ----
    {
        int n8 = 6144 * 4096 / 8;
        k_convert<<<n8 / 256, 256, 0, stream>>>(W_ih, W_ih_b, n8);
    }
    {
        int n8 = 6144 * 2048 / 8;
        k_convert<<<n8 / 256, 256, 0, stream>>>(W_hh, W_hh_b, n8);
    }
    {
        int n8 = 2048 * 256 / 8;
        k_convert<<<n8 / 256, 256, 0, stream>>>(W_o, W_o_b, n8);
        k_convert<<<n8 / 256, 256, 0, stream>>>(W_post, W_p_b, n8);
    }
    {
        int n8 = 2048 * 32 / 8;
        k_convert<<<n8 / 256, 256, 0, stream>>>(W_a, W_a_b, n8);
    }
    {
        int n8 = 32 * 4096 / 8;
        k_convert<<<n8 / 256, 256, 0, stream>>>(W3, W3_b, n8);
    }
    {
        int n8 = B_N * 2304 / 8;
        k_split_state<<<n8 / 256, 256, 0, stream>>>(state, env_b, h0_b, n8);
    }
    {
        int n8 = B_N * 32 / 8;
        k_convert<<<n8 / 256, 256, 0, stream>>>(prev_action, pa_b, n8);
    }

    // ---- chunked middle section ----
    const int nch = B_N / C;
    for (int c = 0; c < nch; ++c) {
        const bf16* envc = env_b + (size_t)c * C * 256;
        const bf16* pac  = pa_b + (size_t)c * C * 32;
        bf16* h0c        = h0_b + (size_t)c * C * 2048;
        bf16* fpc        = fp_b + (size_t)c * C * 2048;
        const float* stc = state + (size_t)c * C * 2304;
        float* nhc = out_nh + (size_t)c * C * 2048;

        dim3 gf(C / 128, F_N / 128);
        // feat_o -> x[:, 0:2048]
        k_gemm<1><<<gf, 256, 0, stream>>>(envc, 256, W_o_b, 256, b_o, x_c, 4096, 256);
        // feat_a -> x[:, 2048:4096]
        k_gemm<1><<<gf, 256, 0, stream>>>(pac, 32, W_a_b, 32, b_a, x_c + 2048, 4096, 32);
        // feat_post (persists full-batch)
        k_gemm<1><<<gf, 256, 0, stream>>>(envc, 256, W_p_b, 256, b_post, fpc, 2048, 256);

        dim3 gg(C / 128, 6144 / 128);
        k_gemm<0><<<gg, 256, 0, stream>>>(x_c, 4096, W_ih_b, 4096, b_ih, gi_c, 6144, 4096);
        k_gemm<0><<<gg, 256, 0, stream>>>(h0c, 2048, W_hh_b, 2048, b_hh, gh_c, 6144, 2048);

        int n8 = C * H_N / 8;
        // k_gate overwrites h0c with h1 (bf16); gh GEMM above already consumed it
        k_gate<<<n8 / 256, 256, 0, stream>>>(gi_c, gh_c, stc, nhc, h0c, n8);
    }

    // ---- last layer: one full-batch MFMA GEMM ----
    k_last<<<B_N / 64, 256, 0, stream>>>(fp_b, h0_b, W3_b, b3, out_action);
}